// Round 7
// baseline (1013.326 us; speedup 1.0000x reference)
//
#include <hip/hip_runtime.h>

__device__ __forceinline__ float lrelu(float v){ return v > 0.f ? v : 0.01f*v; }

// ================= CSR build =================================================
__global__ __launch_bounds__(256) void k_hist(
    const int* __restrict__ ei, int* __restrict__ deg, int E)
{
    int e = blockIdx.x * 256 + threadIdx.x;
    if (e >= E) return;
    atomicAdd(&deg[ei[E + e]], 1);
}

__global__ __launch_bounds__(256) void k_scan1(
    const int* __restrict__ deg, int* __restrict__ rowptr,
    int* __restrict__ bsum, int N)
{
    __shared__ int sh[256];
    int t = threadIdx.x;
    int i = blockIdx.x * 256 + t;
    int v = (i < N) ? deg[i] : 0;
    sh[t] = v;
    __syncthreads();
    #pragma unroll
    for (int off = 1; off < 256; off <<= 1) {
        int add = (t >= off) ? sh[t - off] : 0;
        __syncthreads();
        sh[t] += add;
        __syncthreads();
    }
    if (i < N) rowptr[i] = sh[t] - v;
    if (t == 255) bsum[blockIdx.x] = sh[t];
}

__global__ __launch_bounds__(512) void k_scan2(int* __restrict__ bsum, int nb)
{
    __shared__ int sh[512];
    int t = threadIdx.x;
    int v = (t < nb) ? bsum[t] : 0;
    sh[t] = v;
    __syncthreads();
    #pragma unroll
    for (int off = 1; off < 512; off <<= 1) {
        int add = (t >= off) ? sh[t - off] : 0;
        __syncthreads();
        sh[t] += add;
        __syncthreads();
    }
    if (t < nb) bsum[t] = sh[t] - v;
}

__global__ __launch_bounds__(256) void k_scan3(
    int* __restrict__ rowptr, int* __restrict__ cursor,
    const int* __restrict__ bsum, int N)
{
    int i = blockIdx.x * 256 + threadIdx.x;
    if (i >= N) return;
    int rp = rowptr[i] + bsum[i >> 8];
    rowptr[i] = rp;
    cursor[i] = rp;
}

// packed CSR record: x=eid, y=src, z=dst, w=unused
__global__ __launch_bounds__(256) void k_scatter(
    const int* __restrict__ ei, int* __restrict__ cursor,
    int4* __restrict__ csr, int E)
{
    int e = blockIdx.x * 256 + threadIdx.x;
    if (e >= E) return;
    int s = ei[e];
    int d = ei[E + e];
    int slot = atomicAdd(&cursor[d], 1);
    int4 rec; rec.x = e; rec.y = s; rec.z = d; rec.w = 0;
    csr[slot] = rec;
}

// ============ conv1 aggregation: edge-major, SW-pipelined ====================
#define SPW1 128
__global__ __launch_bounds__(256) void k_agg1(
    const float* __restrict__ x, const float* __restrict__ ea,
    const float* __restrict__ We, const float* __restrict__ be,
    const int4* __restrict__ csr, float* __restrict__ agg, int E)
{
    const int tid = threadIdx.x;
    const int c = tid & 31;
    const int half = (tid >> 5) & 1;
    const int wave = __builtin_amdgcn_readfirstlane((blockIdx.x * 256 + tid) >> 6);
    const long s0 = (long)wave * SPW1;
    if (s0 >= E) return;
    const long send = (s0 + SPW1 < (long)E) ? s0 + SPW1 : (long)E;

    float w[16];
    #pragma unroll
    for (int k = 0; k < 16; ++k) w[k] = We[k * 32 + c];
    const float bias = be[c];

    long sl = s0 + half;
    if (sl >= send) return;

    int4 rec = csr[sl];
    float xv = x[(size_t)rec.y * 32 + c];
    float4 e0, e1, e2, e3;
    {
        const float4* p = reinterpret_cast<const float4*>(ea) + (size_t)rec.x * 4;
        e0 = p[0]; e1 = p[1]; e2 = p[2]; e3 = p[3];
    }
    int cur = rec.z;
    float acc = 0.f;
    bool more = true;
    do {
        long nxt = sl + 2;
        more = (nxt < send);
        int4 recn; float xvn; float4 f0, f1, f2, f3;
        if (more) {
            recn = csr[nxt];
            xvn = x[(size_t)recn.y * 32 + c];
            const float4* p = reinterpret_cast<const float4*>(ea) + (size_t)recn.x * 4;
            f0 = p[0]; f1 = p[1]; f2 = p[2]; f3 = p[3];
        }
        if (rec.z != cur) {
            atomicAdd(&agg[(size_t)cur * 32 + c], acc);
            acc = 0.f; cur = rec.z;
        }
        float m = bias;
        m = fmaf(e0.x, w[0], m);  m = fmaf(e0.y, w[1], m);
        m = fmaf(e0.z, w[2], m);  m = fmaf(e0.w, w[3], m);
        m = fmaf(e1.x, w[4], m);  m = fmaf(e1.y, w[5], m);
        m = fmaf(e1.z, w[6], m);  m = fmaf(e1.w, w[7], m);
        m = fmaf(e2.x, w[8], m);  m = fmaf(e2.y, w[9], m);
        m = fmaf(e2.z, w[10], m); m = fmaf(e2.w, w[11], m);
        m = fmaf(e3.x, w[12], m); m = fmaf(e3.y, w[13], m);
        m = fmaf(e3.z, w[14], m); m = fmaf(e3.w, w[15], m);
        m += xv;
        acc += (m > 0.f ? m : 0.f);
        if (more) {
            rec = recn; xv = xvn;
            e0 = f0; e1 = f1; e2 = f2; e3 = f3;
        }
        sl = nxt;
    } while (more);
    atomicAdd(&agg[(size_t)cur * 32 + c], acc);
}

// ============ conv2 aggregation: edge-major, wave-uniform, SW-pipelined ======
#define SPW2 64
__global__ __launch_bounds__(256) void k_agg2(
    const float* __restrict__ h1, const float* __restrict__ ea,
    const float* __restrict__ We, const float* __restrict__ be,
    const int4* __restrict__ csr, float* __restrict__ agg, int E)
{
    const int tid = threadIdx.x;
    const int c = tid & 63;
    const int wave = __builtin_amdgcn_readfirstlane((blockIdx.x * 256 + tid) >> 6);
    const long s0 = (long)wave * SPW2;
    if (s0 >= E) return;
    const long send = (s0 + SPW2 < (long)E) ? s0 + SPW2 : (long)E;

    float w[16];
    #pragma unroll
    for (int k = 0; k < 16; ++k) w[k] = We[k * 64 + c];
    const float bias = be[c];

    long sl = s0;
    int4 rec = csr[sl];
    float hv = h1[(size_t)rec.y * 64 + c];
    float4 e0, e1, e2, e3;
    {
        const float4* p = reinterpret_cast<const float4*>(ea) + (size_t)rec.x * 4;
        e0 = p[0]; e1 = p[1]; e2 = p[2]; e3 = p[3];
    }
    int cur = rec.z;
    bool owned = false;
    float acc = 0.f;
    bool more = true;
    do {
        long nxt = sl + 1;
        more = (nxt < send);
        int4 recn; float hvn; float4 f0, f1, f2, f3;
        if (more) {
            recn = csr[nxt];
            hvn = h1[(size_t)recn.y * 64 + c];
            const float4* p = reinterpret_cast<const float4*>(ea) + (size_t)recn.x * 4;
            f0 = p[0]; f1 = p[1]; f2 = p[2]; f3 = p[3];
        }
        if (rec.z != cur) {
            if (owned) agg[(size_t)cur * 64 + c] = acc;
            else       atomicAdd(&agg[(size_t)cur * 64 + c], acc);
            acc = 0.f; cur = rec.z; owned = true;
        }
        float m = bias;
        m = fmaf(e0.x, w[0], m);  m = fmaf(e0.y, w[1], m);
        m = fmaf(e0.z, w[2], m);  m = fmaf(e0.w, w[3], m);
        m = fmaf(e1.x, w[4], m);  m = fmaf(e1.y, w[5], m);
        m = fmaf(e1.z, w[6], m);  m = fmaf(e1.w, w[7], m);
        m = fmaf(e2.x, w[8], m);  m = fmaf(e2.y, w[9], m);
        m = fmaf(e2.z, w[10], m); m = fmaf(e2.w, w[11], m);
        m = fmaf(e3.x, w[12], m); m = fmaf(e3.y, w[13], m);
        m = fmaf(e3.z, w[14], m); m = fmaf(e3.w, w[15], m);
        m += hv;
        acc += (m > 0.f ? m : 0.f);
        if (more) {
            rec = recn; hv = hvn;
            e0 = f0; e1 = f1; e2 = f2; e3 = f3;
        }
        sl = nxt;
    } while (more);
    atomicAdd(&agg[(size_t)cur * 64 + c], acc);
}

// ============ conv1 node nn, fused; row in registers, ts-only LDS ============
__global__ __launch_bounds__(256, 4) void k_mlp1(
    const float* __restrict__ x, const float* __restrict__ agg1,
    const float* __restrict__ W1a, const float* __restrict__ b1a,
    const float* __restrict__ W1b, const float* __restrict__ b1b,
    float* __restrict__ h1, int N)
{
    __shared__ float ts[64][33];
    const int tid = threadIdx.x;
    const int n0 = blockIdx.x * 64;
    const int row = tid & 63;
    const int grp = __builtin_amdgcn_readfirstlane(tid >> 6);
    const int g = n0 + row;

    float hv[32];
    if (g < N) {
        const float4* xp = reinterpret_cast<const float4*>(x) + (size_t)g * 8;
        const float4* ap = reinterpret_cast<const float4*>(agg1) + (size_t)g * 8;
        #pragma unroll
        for (int q = 0; q < 8; ++q) {
            float4 a = xp[q], b = ap[q];
            hv[4*q+0]=a.x+b.x; hv[4*q+1]=a.y+b.y;
            hv[4*q+2]=a.z+b.z; hv[4*q+3]=a.w+b.w;
        }
    } else {
        #pragma unroll
        for (int q = 0; q < 32; ++q) hv[q] = 0.f;
    }

    {
        const int c0 = grp * 8;
        float acc[8];
        #pragma unroll
        for (int i = 0; i < 8; ++i) acc[i] = b1a[c0 + i];
        for (int k = 0; k < 32; ++k) {
            float h = hv[k];
            const float* w = W1a + k*32 + c0;
            #pragma unroll
            for (int i = 0; i < 8; ++i) acc[i] = fmaf(h, w[i], acc[i]);
        }
        #pragma unroll
        for (int i = 0; i < 8; ++i) ts[row][c0 + i] = lrelu(acc[i]);
    }
    __syncthreads();

    {
        const int c0 = grp * 16;
        float acc[16];
        #pragma unroll
        for (int i = 0; i < 16; ++i) acc[i] = b1b[c0 + i];
        for (int k = 0; k < 32; ++k) {
            float tv = ts[row][k];
            const float* w = W1b + k*64 + c0;
            #pragma unroll
            for (int i = 0; i < 16; ++i) acc[i] = fmaf(tv, w[i], acc[i]);
        }
        if (g < N) {
            float4* op = reinterpret_cast<float4*>(h1) + (size_t)g*16 + (c0>>2);
            #pragma unroll
            for (int q = 0; q < 4; ++q) {
                float4 o;
                o.x = lrelu(acc[4*q+0]); o.y = lrelu(acc[4*q+1]);
                o.z = lrelu(acc[4*q+2]); o.w = lrelu(acc[4*q+3]);
                op[q] = o;
            }
        }
    }
}

// ============ conv2 node nn + fused global_add_pool ==========================
// Per wave: lane = row (64 rows/block), grp = column group. Phase-2 output is
// pooled directly into gbuf via segmented 64-lane butterfly + atomics.
// waves_per_eu(4,4) pins the allocator at 4 waves/EU (<=128 VGPR, no spill).
__global__ __attribute__((amdgpu_flat_work_group_size(256, 256)))
           __attribute__((amdgpu_waves_per_eu(4, 4)))
void k_mlp2(
    const float* __restrict__ h1, const float* __restrict__ agg2,
    const float* __restrict__ W2a, const float* __restrict__ b2a,
    const float* __restrict__ W2b, const float* __restrict__ b2b,
    const int* __restrict__ batch, float* __restrict__ gbuf, int N)
{
    __shared__ float ts[64][129];
    const int tid = threadIdx.x;
    const int n0 = blockIdx.x * 64;
    const int row = tid & 63;
    const int grp = __builtin_amdgcn_readfirstlane(tid >> 6);
    const int g = n0 + row;
    const bool valid = (g < N);
    const int b_real = batch[valid ? g : (N - 1)];
    const int bfirst = __shfl(b_real, 0);
    const int blast  = __shfl(b_real, 63);

    // phase 1: ts[row][32*grp .. +32] = lrelu(rowvec @ W2a + b2a)
    // rowvec (h1+agg2) loaded in 4 chunks of 16 to bound live registers.
    {
        const int c0 = grp * 32;
        float acc[32];
        #pragma unroll
        for (int i = 0; i < 32; ++i) acc[i] = b2a[c0 + i];
        #pragma unroll 1
        for (int kc = 0; kc < 4; ++kc) {
            float hv[16];
            if (valid) {
                const float4* xp = reinterpret_cast<const float4*>(h1)
                                   + (size_t)g * 16 + kc * 4;
                const float4* ap = reinterpret_cast<const float4*>(agg2)
                                   + (size_t)g * 16 + kc * 4;
                #pragma unroll
                for (int q = 0; q < 4; ++q) {
                    float4 a = xp[q], b = ap[q];
                    hv[4*q+0]=a.x+b.x; hv[4*q+1]=a.y+b.y;
                    hv[4*q+2]=a.z+b.z; hv[4*q+3]=a.w+b.w;
                }
            } else {
                #pragma unroll
                for (int q = 0; q < 16; ++q) hv[q] = 0.f;
            }
            #pragma unroll
            for (int k2 = 0; k2 < 16; ++k2) {
                const float* w = W2a + (kc*16 + k2)*128 + c0;
                float h = hv[k2];
                #pragma unroll
                for (int i = 0; i < 32; ++i) acc[i] = fmaf(h, w[i], acc[i]);
            }
        }
        #pragma unroll
        for (int i = 0; i < 32; ++i) ts[row][c0 + i] = lrelu(acc[i]);
    }
    __syncthreads();

    // phase 2 + pool: two 32-col chunks; each chunk butterfly-reduced over the
    // 64 rows (segmented by graph id) and atomically added to gbuf.
    #pragma unroll 1
    for (int ch = 0; ch < 2; ++ch) {
        const int c0 = grp * 64 + ch * 32;
        float acc[32];
        #pragma unroll
        for (int i = 0; i < 32; ++i) acc[i] = b2b[c0 + i];
        for (int k = 0; k < 128; ++k) {
            float tv = ts[row][k];
            const float* w = W2b + k*256 + c0;
            #pragma unroll
            for (int i = 0; i < 32; ++i) acc[i] = fmaf(tv, w[i], acc[i]);
        }
        #pragma unroll
        for (int i = 0; i < 32; ++i) acc[i] = lrelu(acc[i]);

        for (int gi = bfirst; gi <= blast; ++gi) {   // sorted batch: 1-2 iters
            const bool mine = valid && (b_real == gi);
            float out = 0.f;
            #pragma unroll
            for (int i = 0; i < 32; ++i) {
                float v = mine ? acc[i] : 0.f;
                v += __shfl_xor(v, 1);
                v += __shfl_xor(v, 2);
                v += __shfl_xor(v, 4);
                v += __shfl_xor(v, 8);
                v += __shfl_xor(v, 16);
                v += __shfl_xor(v, 32);
                if (row == i) out = v;
            }
            if (row < 32)
                atomicAdd(&gbuf[(size_t)gi * 256 + c0 + row], out);
        }
    }
}

// ---------------- head MLP -----------------------------------------------------
__global__ __launch_bounds__(256) void k_head(
    const float* __restrict__ g,
    const float* __restrict__ Wf0, const float* __restrict__ bf0,
    const float* __restrict__ Wf1, const float* __restrict__ bf1,
    const float* __restrict__ Wf2, const float* __restrict__ bf2,
    const float* __restrict__ Wr,  const float* __restrict__ br,
    float* __restrict__ out)
{
    __shared__ float buf[256];
    __shared__ float t0[128];
    __shared__ float t1[64];
    __shared__ float t2[32];
    int gid = blockIdx.x, tid = threadIdx.x;
    buf[tid] = g[(size_t)gid*256 + tid];
    __syncthreads();
    if (tid < 128) {
        float acc = bf0[tid];
        for (int k = 0; k < 256; ++k) acc = fmaf(buf[k], Wf0[k*128 + tid], acc);
        t0[tid] = lrelu(acc);
    }
    __syncthreads();
    if (tid < 64) {
        float acc = bf1[tid];
        for (int k = 0; k < 128; ++k) acc = fmaf(t0[k], Wf1[k*64 + tid], acc);
        t1[tid] = lrelu(acc);
    }
    __syncthreads();
    if (tid < 32) {
        float acc = bf2[tid];
        for (int k = 0; k < 64; ++k) acc = fmaf(t1[k], Wf2[k*32 + tid], acc);
        t2[tid] = lrelu(acc);
    }
    __syncthreads();
    if (tid == 0) {
        float acc = br[0];
        for (int k = 0; k < 32; ++k) acc = fmaf(t2[k], Wr[k], acc);
        out[gid] = acc;
    }
}

extern "C" void kernel_launch(void* const* d_in, const int* in_sizes, int n_in,
                              void* d_out, int out_size, void* d_ws, size_t ws_size,
                              hipStream_t stream)
{
    const float* x     = (const float*)d_in[0];
    const int*   ei    = (const int*)d_in[1];
    const float* ea    = (const float*)d_in[2];
    const int*   batch = (const int*)d_in[3];
    const float* We1=(const float*)d_in[4],  *be1=(const float*)d_in[5];
    const float* W1a=(const float*)d_in[6],  *b1a=(const float*)d_in[7];
    const float* W1b=(const float*)d_in[8],  *b1b=(const float*)d_in[9];
    const float* We2=(const float*)d_in[10], *be2=(const float*)d_in[11];
    const float* W2a=(const float*)d_in[12], *b2a=(const float*)d_in[13];
    const float* W2b=(const float*)d_in[14], *b2b=(const float*)d_in[15];
    const float* Wf0=(const float*)d_in[16], *bf0=(const float*)d_in[17];
    const float* Wf1=(const float*)d_in[18], *bf1=(const float*)d_in[19];
    const float* Wf2=(const float*)d_in[20], *bf2=(const float*)d_in[21];
    const float* Wr =(const float*)d_in[22], *br =(const float*)d_in[23];

    const int N = in_sizes[0] / 32;
    const int E = in_sizes[1] / 2;
    const int G = out_size;
    const int nb = (N + 255) / 256;
    const int nb64 = (N + 63) / 64;

    // ---- workspace layout ----
    char* p = (char*)d_ws;
    int*   deg     = (int*)p;                 p += (size_t)N * 4;
    float* gbuf    = (float*)p;               p += (size_t)G * 256 * 4;
    float* agg1    = (float*)p;               p += (size_t)N * 32 * 4;
    float* agg2    = (float*)p;               p += (size_t)N * 64 * 4;
    size_t zero_bytes = (size_t)(p - (char*)d_ws);
    int*   rowptr  = (int*)p;                 p += (size_t)N * 4;
    int*   cursor  = (int*)p;                 p += (size_t)N * 4;
    int*   bsum    = (int*)p;                 p += 512 * 4;
    p = (char*)(((uintptr_t)p + 15) & ~(uintptr_t)15);
    int4*  csr     = (int4*)p;                p += (size_t)E * 16;
    float* h1      = (float*)p;               p += (size_t)N * 64 * 4;

    hipMemsetAsync(d_ws, 0, zero_bytes, stream);

    int eb = (E + 255) / 256;

    // CSR build
    k_hist   <<<eb, 256, 0, stream>>>(ei, deg, E);
    k_scan1  <<<nb, 256, 0, stream>>>(deg, rowptr, bsum, N);
    k_scan2  <<<1, 512, 0, stream>>>(bsum, nb);
    k_scan3  <<<nb, 256, 0, stream>>>(rowptr, cursor, bsum, N);
    k_scatter<<<eb, 256, 0, stream>>>(ei, cursor, csr, E);

    // conv1
    {
        int waves = (E + SPW1 - 1) / SPW1;
        int blocks = (waves + 3) / 4;
        k_agg1<<<blocks, 256, 0, stream>>>(x, ea, We1, be1, csr, agg1, E);
    }
    k_mlp1<<<nb64, 256, 0, stream>>>(x, agg1, W1a, b1a, W1b, b1b, h1, N);

    // conv2 (+ fused pool)
    {
        int waves = (E + SPW2 - 1) / SPW2;
        int blocks = (waves + 3) / 4;
        k_agg2<<<blocks, 256, 0, stream>>>(h1, ea, We2, be2, csr, agg2, E);
    }
    k_mlp2<<<nb64, 256, 0, stream>>>(h1, agg2, W2a, b2a, W2b, b2b,
                                     batch, gbuf, N);

    // head
    k_head<<<G, 256, 0, stream>>>(gbuf, Wf0, bf0, Wf1, bf1, Wf2, bf2, Wr, br,
                                  (float*)d_out);
}